// Round 7
// baseline (6099.884 us; speedup 1.0000x reference)
//
#include <hip/hip_runtime.h>
#include <math.h>

#define NN 512
#define DD 8192

// ---------------- row-norm scales: scale[m][r] = 1 / max(||row||, 1e-6) ----------------
__global__ __launch_bounds__(256) void norm_kernel(
    const float* __restrict__ a0, const float* __restrict__ a1,
    const float* __restrict__ a2, float* __restrict__ scales) {
  const float* mats[3] = {a0, a1, a2};
  const int m = blockIdx.y;
  const int row = blockIdx.x;
  const float* x = mats[m] + (size_t)row * DD;
  const int tid = threadIdx.x;
  float s = 0.f;
  for (int k = tid * 4; k < DD; k += 256 * 4) {
    const float4 v = *(const float4*)(x + k);
    s += v.x * v.x + v.y * v.y + v.z * v.z + v.w * v.w;
  }
#pragma unroll
  for (int off = 32; off > 0; off >>= 1) s += __shfl_down(s, off);
  __shared__ float ws[4];
  if ((tid & 63) == 0) ws[tid >> 6] = s;
  __syncthreads();
  if (tid == 0) {
    const float t = ws[0] + ws[1] + ws[2] + ws[3];
    scales[m * NN + row] = 1.0f / fmaxf(sqrtf(t), 1e-6f);
  }
}

// ---------------- cost_p = 1 - (A B^T) * sa * sb, p: (0:1->2, 1:2->3, 2:3->1) ----------
// R3-proven BK=32 version.
__global__ __launch_bounds__(256) void cost_gemm_kernel(
    const float* __restrict__ a0, const float* __restrict__ a1,
    const float* __restrict__ a2, const float* __restrict__ scales,
    float* __restrict__ cost_all) {
  const float* mats[3] = {a0, a1, a2};
  const int p = blockIdx.z;
  const int pA = p, pB = (p + 1) % 3;
  const float* A = mats[pA];
  const float* B = mats[pB];
  float* C = cost_all + (size_t)p * NN * NN;

  __shared__ float lds_a[32 * 64];
  __shared__ float lds_b[32 * 64];

  const int tid = threadIdx.x;
  const int rowBase = blockIdx.y * 64;
  const int colBase = blockIdx.x * 64;

  const int lr = tid & 63;   // row within tile for staging
  const int lq = tid >> 6;   // 0..3

  const float* Arow = A + (size_t)(rowBase + lr) * DD;
  const float* Brow = B + (size_t)(colBase + lr) * DD;

  float acc[4][4];
#pragma unroll
  for (int i = 0; i < 4; ++i)
#pragma unroll
    for (int j = 0; j < 4; ++j) acc[i][j] = 0.f;

  const int tx = tid & 15, ty = tid >> 4;

  for (int kb = 0; kb < DD; kb += 32) {
#pragma unroll
    for (int qq = 0; qq < 2; ++qq) {
      const int q = lq + qq * 4;  // 0..7, covers k offsets q*4..q*4+3
      const float4 av = *(const float4*)(Arow + kb + q * 4);
      const float4 bv = *(const float4*)(Brow + kb + q * 4);
      lds_a[(q * 4 + 0) * 64 + lr] = av.x;
      lds_a[(q * 4 + 1) * 64 + lr] = av.y;
      lds_a[(q * 4 + 2) * 64 + lr] = av.z;
      lds_a[(q * 4 + 3) * 64 + lr] = av.w;
      lds_b[(q * 4 + 0) * 64 + lr] = bv.x;
      lds_b[(q * 4 + 1) * 64 + lr] = bv.y;
      lds_b[(q * 4 + 2) * 64 + lr] = bv.z;
      lds_b[(q * 4 + 3) * 64 + lr] = bv.w;
    }
    __syncthreads();
#pragma unroll
    for (int k = 0; k < 32; ++k) {
      const float4 a4 = *(const float4*)(&lds_a[k * 64 + ty * 4]);
      const float4 b4 = *(const float4*)(&lds_b[k * 64 + tx * 4]);
      const float as0[4] = {a4.x, a4.y, a4.z, a4.w};
      const float bs0[4] = {b4.x, b4.y, b4.z, b4.w};
#pragma unroll
      for (int ii = 0; ii < 4; ++ii)
#pragma unroll
        for (int jj = 0; jj < 4; ++jj)
          acc[ii][jj] = fmaf(as0[ii], bs0[jj], acc[ii][jj]);
    }
    __syncthreads();
  }

#pragma unroll
  for (int ii = 0; ii < 4; ++ii) {
    const int gr = rowBase + ty * 4 + ii;
    const float sa = scales[pA * NN + gr];
#pragma unroll
    for (int jj = 0; jj < 4; ++jj) {
      const int gc = colBase + tx * 4 + jj;
      const float sb = scales[pB * NN + gc];
      C[gr * NN + gc] = 1.0f - acc[ii][jj] * sa * sb;
    }
  }
}

// ---------------- exact JV shortest-augmenting-path LAP, ONE WAVE per problem ----------
// Software-pipelined Dijkstra step: the relax STATE update (selv/path fmin+cndmask) and
// the minv readlane are deferred into the NEXT iteration's load shadow. The post-load
// critical chain is only: r = cvt(cf)+base -> 3-level r-tree -> combine with old-tree
// -> key -> DPP -> ballot -> payload readlane. Exactness: argmin over min(old,r) ==
// combine(argmin old, argmin r) with min-payload tie-break (any col achieving the global
// min V has old==V or r==V; each subtree returns its smallest such col). Strict-< and
// identical operand values everywhere => same extraction order as reference solve_lap_np.

// bijective LDS index swizzle: owner-lane accesses (stride 8) become conflict-free
__device__ __forceinline__ int SW(int c) { return ((c & 7) << 6) | (c >> 3); }

// full-wave (64-lane) u32 min via DPP; returns broadcast scalar
__device__ __forceinline__ unsigned wave_min_u32(unsigned x) {
  int t;
  t = __builtin_amdgcn_update_dpp((int)x, (int)x, 0x111, 0xf, 0xf, false);  // row_shr:1
  x = ((unsigned)t < x) ? (unsigned)t : x;
  t = __builtin_amdgcn_update_dpp((int)x, (int)x, 0x112, 0xf, 0xf, false);  // row_shr:2
  x = ((unsigned)t < x) ? (unsigned)t : x;
  t = __builtin_amdgcn_update_dpp((int)x, (int)x, 0x114, 0xf, 0xf, false);  // row_shr:4
  x = ((unsigned)t < x) ? (unsigned)t : x;
  t = __builtin_amdgcn_update_dpp((int)x, (int)x, 0x118, 0xf, 0xf, false);  // row_shr:8
  x = ((unsigned)t < x) ? (unsigned)t : x;
  t = __builtin_amdgcn_update_dpp((int)x, (int)x, 0x142, 0xf, 0xf, false);  // row_bcast:15
  x = ((unsigned)t < x) ? (unsigned)t : x;
  t = __builtin_amdgcn_update_dpp((int)x, (int)x, 0x143, 0xf, 0xf, false);  // row_bcast:31
  x = ((unsigned)t < x) ? (unsigned)t : x;
  return (unsigned)__builtin_amdgcn_readlane((int)x, 63);
}

__device__ __forceinline__ double readlane_f64(double x, int lane) {
  const long long b = __double_as_longlong(x);
  const int lo = __builtin_amdgcn_readlane((int)(b & 0xffffffffLL), lane);
  const int hi = __builtin_amdgcn_readlane((int)(b >> 32), lane);
  return __longlong_as_double(((long long)hi << 32) | (unsigned long long)(unsigned)lo);
}

__device__ __forceinline__ unsigned long long f64key(double x) {
  const long long b = __double_as_longlong(x);
  return (b < 0) ? ~(unsigned long long)b
                 : ((unsigned long long)b | 0x8000000000000000ULL);
}

// 8 -> 1 min-tree with payload; strict < keeps the SMALLEST index on ties
#define TREE8(v, pq, oV, oP)                                                   \
  do {                                                                         \
    const bool t01 = (v)[1] < (v)[0];                                          \
    const double a0 = t01 ? (v)[1] : (v)[0];                                   \
    const unsigned b0 = t01 ? (pq)[1] : (pq)[0];                               \
    const bool t23 = (v)[3] < (v)[2];                                          \
    const double a1 = t23 ? (v)[3] : (v)[2];                                   \
    const unsigned b1 = t23 ? (pq)[3] : (pq)[2];                               \
    const bool t45 = (v)[5] < (v)[4];                                          \
    const double a2 = t45 ? (v)[5] : (v)[4];                                   \
    const unsigned b2 = t45 ? (pq)[5] : (pq)[4];                               \
    const bool t67 = (v)[7] < (v)[6];                                          \
    const double a3 = t67 ? (v)[7] : (v)[6];                                   \
    const unsigned b3 = t67 ? (pq)[7] : (pq)[6];                               \
    const bool ta = a1 < a0;                                                   \
    const double c0_ = ta ? a1 : a0;                                           \
    const unsigned d0_ = ta ? b1 : b0;                                         \
    const bool tb = a3 < a2;                                                   \
    const double c1_ = tb ? a3 : a2;                                           \
    const unsigned d1_ = tb ? b3 : b2;                                         \
    const bool tc = c1_ < c0_;                                                 \
    (oV) = tc ? c1_ : c0_;                                                     \
    (oP) = tc ? d1_ : d0_;                                                     \
  } while (0)

__global__ __launch_bounds__(64) void lap_kernel(
    const float* __restrict__ cost_all, float* __restrict__ out) {
  const int p = blockIdx.x;
  const float* cost = cost_all + (size_t)p * NN * NN;
  float* outp = out + (size_t)p * NN * NN;
  const int tid = threadIdx.x;  // 0..63

  __shared__ double sh_u[NN];        // u[row] at SW(row)
  __shared__ double sh_shortest[NN]; // frozen shortest[col] at SW(col)
  __shared__ int sh_path[NN];        // path[col] at SW(col)
  __shared__ int sh_x[NN];           // col4row[row] at SW(row)
  __shared__ int sh_y[NN];           // row4col[col] at SW(col)

  const double INF = __builtin_inf();

#pragma unroll
  for (int q = 0; q < 8; ++q) {
    const int e = tid * 8 + q;
    sh_x[SW(e)] = -1;
    sh_y[SW(e)] = -1;
    sh_u[SW(e)] = 0.0;
  }
  double myV[8];
#pragma unroll
  for (int q = 0; q < 8; ++q) myV[q] = 0.0;  // v[8*tid+q], owner-only
  __syncthreads();

  for (int cur_row = 0; cur_row < NN; ++cur_row) {
    double selv[8];   // shortest (state as of the PREVIOUS iteration's publish point)
    double vAdj[8];   // myV, poisoned to -INF when col enters SC
    double frz[8];    // frozen shortest at SC-add time (= minv then)
    double rPrev[8];  // previous iteration's relax values (pending application)
    int myPath[8];
    unsigned pl[8];   // payload: (q<<10) | (row4col[col]+1)  (phase-constant)
#pragma unroll
    for (int q = 0; q < 8; ++q) {
      selv[q] = INF;
      vAdj[q] = myV[q];
      frz[q] = 0.0;
      rPrev[q] = INF;   // sentinel: first-iteration apply is a no-op
      myPath[q] = 0;
    }
#pragma unroll
    for (int q = 0; q < 8; ++q)
      pl[q] = ((unsigned)q << 10) | (unsigned)(sh_y[SW(tid * 8 + q)] + 1);

    unsigned scMask = 0, srMask = 0;
    int i = cur_row;       // uniform
    double minv = 0.0;     // uniform (recomputed from lvW/srcL each shadow)
    double lvW = 0.0;      // per-lane winner value of prev iter (0 => minv=0 initially)
    int srcL = 0;          // uniform winner lane of prev iter
    int iPrev = 0;
    int pendQ = -1, pendLane = 0;
    int sink = -1;

    while (true) {
      // ---- issue dependent loads FIRST ----
      const float4 c0 = *(const float4*)(cost + (size_t)i * NN + tid * 8);
      const float4 c1 = *(const float4*)(cost + (size_t)i * NN + tid * 8 + 4);
      const double u_i = sh_u[SW(i)];
      if ((i >> 3) == tid) srMask |= 1u << (i & 7);

      // ---- shadow work (independent of c0/c1) ----
      minv = readlane_f64(lvW, srcL);  // prev extraction value (0.0 on first iter)
      // apply previous iteration's relax to the state (deferred fmin/path update)
#pragma unroll
      for (int q = 0; q < 8; ++q) {
        const bool cnd = rPrev[q] < selv[q];
        myPath[q] = cnd ? iPrev : myPath[q];
        selv[q] = fmin(selv[q], rPrev[q]);
      }
      // apply pending SC-add for the col extracted last iteration
      if (pendQ >= 0) {
        const bool me = (tid == pendLane);
#define APPLY_SC(K)                                                     \
        if (pendQ == K) {                                               \
          if (me) {                                                     \
            selv[K] = INF; vAdj[K] = -INF; frz[K] = minv;               \
            scMask |= 1u << K;                                          \
          }                                                             \
        }
        APPLY_SC(0) APPLY_SC(1) APPLY_SC(2) APPLY_SC(3)
        APPLY_SC(4) APPLY_SC(5) APPLY_SC(6) APPLY_SC(7)
#undef APPLY_SC
      }
      // old-state tournament (per-lane argmin of selv, ties -> smallest q)
      double oV;
      unsigned oP;
      TREE8(selv, pl, oV, oP);
      // relax bases: r = cf + ((minv - u_i) - vAdj)
      const double mu = minv - u_i;
      double base[8];
#pragma unroll
      for (int q = 0; q < 8; ++q) base[q] = mu - vAdj[q];  // SC cols -> +INF

      // ---- post-load critical chain ----
      const float cf[8] = {c0.x, c0.y, c0.z, c0.w, c1.x, c1.y, c1.z, c1.w};
#pragma unroll
      for (int q = 0; q < 8; ++q) rPrev[q] = (double)cf[q] + base[q];
      double rV;
      unsigned rP;
      TREE8(rPrev, pl, rV, rP);
      // combine old-tree and r-tree (exact; equal values -> smaller payload = smaller col)
      const bool rlt = rV < oV;
      const bool olt = oV < rV;
      const double wV = rlt ? rV : oV;
      const unsigned pmin = (oP < rP) ? oP : rP;
      const unsigned wP = rlt ? rP : (olt ? oP : pmin);
      // exact cross-lane argmin via sortable key
      const unsigned long long kk = f64key(wV);
      const unsigned hi = (unsigned)(kk >> 32);
      const unsigned lo = (unsigned)kk;
      const unsigned minhi = wave_min_u32(hi);
      unsigned long long bal = __ballot(hi == minhi);
      int srcLane;
      if (__popcll(bal) == 1) {  // unique hi-key => unique global min (common case)
        srcLane = __ffsll(bal) - 1;
      } else {
        const unsigned lo2 = (hi == minhi) ? lo : 0xFFFFFFFFu;
        const unsigned minlo = wave_min_u32(lo2);
        bal = __ballot((hi == minhi) && (lo == minlo));
        srcLane = __ffsll(bal) - 1;  // lowest lane = smallest column on exact ties
      }
      const unsigned pw = (unsigned)__builtin_amdgcn_readlane((int)wP, srcLane);
      const int qb = (int)(pw >> 10);
      const int r4 = (int)(pw & 0x3FFu) - 1;
      // hand off to next iteration's shadow
      lvW = wV;
      srcL = srcLane;
      iPrev = i;
      pendQ = qb;
      pendLane = srcLane;
      if (r4 < 0) {  // unmatched column: sink
        sink = srcLane * 8 + qb;
        break;
      }
      i = r4;
    }

    // ---- drain the pipeline: apply the final iteration's pending updates ----
    minv = readlane_f64(lvW, srcL);  // sink extraction value
#pragma unroll
    for (int q = 0; q < 8; ++q) {
      const bool cnd = rPrev[q] < selv[q];
      myPath[q] = cnd ? iPrev : myPath[q];   // path[sink] may be set here - required
      selv[q] = fmin(selv[q], rPrev[q]);
    }
    {
      const bool me = (tid == pendLane);
#define APPLY_SC(K)                                                     \
      if (pendQ == K) {                                                 \
        if (me) {                                                       \
          selv[K] = INF; vAdj[K] = -INF; frz[K] = minv;                 \
          scMask |= 1u << K;                                            \
        }                                                               \
      }
      APPLY_SC(0) APPLY_SC(1) APPLY_SC(2) APPLY_SC(3)
      APPLY_SC(4) APPLY_SC(5) APPLY_SC(6) APPLY_SC(7)
#undef APPLY_SC
    }

    // publish frozen shortest + path (only SC cols are ever read back)
#pragma unroll
    for (int q = 0; q < 8; ++q) {
      sh_shortest[SW(tid * 8 + q)] = frz[q];
      sh_path[SW(tid * 8 + q)] = myPath[q];
    }
    __syncthreads();
    // dual updates (before augmentation, matching reference)
#pragma unroll
    for (int q = 0; q < 8; ++q) {
      const int row = tid * 8 + q;
      if (row == cur_row) {
        sh_u[SW(row)] += minv;
      } else if (srMask & (1u << q)) {
        sh_u[SW(row)] += minv - sh_shortest[SW(sh_x[SW(row)])];
      }
      if (scMask & (1u << q)) myV[q] -= minv - frz[q];  // sink col: delta 0 (frz=minv)
    }
    __syncthreads();
    // augment along the alternating path (short chain, lane 0)
    if (tid == 0) {
      int j = sink;
      while (true) {
        const int pi = sh_path[SW(j)];
        sh_y[SW(j)] = pi;
        const int tmp = sh_x[SW(pi)];
        sh_x[SW(pi)] = j;
        j = tmp;
        if (pi == cur_row) break;
      }
    }
    __syncthreads();  // publish matching for next phase
  }

#pragma unroll
  for (int q = 0; q < 8; ++q) {
    const int row = tid * 8 + q;
    outp[(size_t)row * NN + sh_x[SW(row)]] = 1.0f;
  }
}

extern "C" void kernel_launch(void* const* d_in, const int* in_sizes, int n_in,
                              void* d_out, int out_size, void* d_ws, size_t ws_size,
                              hipStream_t stream) {
  const float* un1 = (const float*)d_in[0];
  const float* un2 = (const float*)d_in[1];
  const float* un3 = (const float*)d_in[2];
  float* out = (float*)d_out;

  float* cost = (float*)d_ws;                       // 3 * 512 * 512 floats
  float* scales = cost + (size_t)3 * NN * NN;       // 3 * 512 floats

  hipMemsetAsync(d_out, 0, (size_t)out_size * sizeof(float), stream);

  norm_kernel<<<dim3(NN, 3), 256, 0, stream>>>(un1, un2, un3, scales);
  cost_gemm_kernel<<<dim3(NN / 64, NN / 64, 3), 256, 0, stream>>>(un1, un2, un3, scales, cost);
  lap_kernel<<<3, 64, 0, stream>>>(cost, out);
}

// Round 8
// 5753.254 us; speedup vs baseline: 1.0602x; 1.0602x over previous
//
#include <hip/hip_runtime.h>
#include <math.h>

#define NN 512
#define DD 8192

// ---------------- row-norm scales: scale[m][r] = 1 / max(||row||, 1e-6) ----------------
__global__ __launch_bounds__(256) void norm_kernel(
    const float* __restrict__ a0, const float* __restrict__ a1,
    const float* __restrict__ a2, float* __restrict__ scales) {
  const float* mats[3] = {a0, a1, a2};
  const int m = blockIdx.y;
  const int row = blockIdx.x;
  const float* x = mats[m] + (size_t)row * DD;
  const int tid = threadIdx.x;
  float s = 0.f;
  for (int k = tid * 4; k < DD; k += 256 * 4) {
    const float4 v = *(const float4*)(x + k);
    s += v.x * v.x + v.y * v.y + v.z * v.z + v.w * v.w;
  }
#pragma unroll
  for (int off = 32; off > 0; off >>= 1) s += __shfl_down(s, off);
  __shared__ float ws[4];
  if ((tid & 63) == 0) ws[tid >> 6] = s;
  __syncthreads();
  if (tid == 0) {
    const float t = ws[0] + ws[1] + ws[2] + ws[3];
    scales[m * NN + row] = 1.0f / fmaxf(sqrtf(t), 1e-6f);
  }
}

// ---------------- cost_p = 1 - (A B^T) * sa * sb, p: (0:1->2, 1:2->3, 2:3->1) ----------
// 64x64 tile, BK=32, 512 threads (8 waves -> 2 waves/SIMD for TLP; R3's 256-thread
// version ran 1 wave/SIMD and exposed every LDS/barrier stall). Per-thread 4x2 output.
__global__ __launch_bounds__(512) void cost_gemm_kernel(
    const float* __restrict__ a0, const float* __restrict__ a1,
    const float* __restrict__ a2, const float* __restrict__ scales,
    float* __restrict__ cost_all) {
  const float* mats[3] = {a0, a1, a2};
  const int p = blockIdx.z;
  const int pA = p, pB = (p + 1) % 3;
  const float* A = mats[pA];
  const float* B = mats[pB];
  float* C = cost_all + (size_t)p * NN * NN;

  __shared__ float lds_a[32 * 64];  // [k][row]
  __shared__ float lds_b[32 * 64];  // [k][col]

  const int tid = threadIdx.x;
  const int rowBase = blockIdx.y * 64;
  const int colBase = blockIdx.x * 64;

  // staging: thread loads 1 float4 per matrix: row = tid&63, k-offset = (tid>>6)*4
  const int sr = tid & 63;
  const int sk = (tid >> 6) * 4;  // 0,4,...,28

  const float* Arow = A + (size_t)(rowBase + sr) * DD + sk;
  const float* Brow = B + (size_t)(colBase + sr) * DD + sk;

  // compute mapping: tx = col-pair 0..31, ty = row-quad 0..15
  const int tx = tid & 31;
  const int ty = tid >> 5;

  float acc[4][2];
#pragma unroll
  for (int i = 0; i < 4; ++i) {
    acc[i][0] = 0.f;
    acc[i][1] = 0.f;
  }

  for (int kb = 0; kb < DD; kb += 32) {
    const float4 av = *(const float4*)(Arow + kb);
    const float4 bv = *(const float4*)(Brow + kb);
    lds_a[(sk + 0) * 64 + sr] = av.x;
    lds_a[(sk + 1) * 64 + sr] = av.y;
    lds_a[(sk + 2) * 64 + sr] = av.z;
    lds_a[(sk + 3) * 64 + sr] = av.w;
    lds_b[(sk + 0) * 64 + sr] = bv.x;
    lds_b[(sk + 1) * 64 + sr] = bv.y;
    lds_b[(sk + 2) * 64 + sr] = bv.z;
    lds_b[(sk + 3) * 64 + sr] = bv.w;
    __syncthreads();
#pragma unroll
    for (int k = 0; k < 32; ++k) {
      const float4 a4 = *(const float4*)(&lds_a[k * 64 + ty * 4]);
      const float2 b2 = *(const float2*)(&lds_b[k * 64 + tx * 2]);
      const float as0[4] = {a4.x, a4.y, a4.z, a4.w};
#pragma unroll
      for (int ii = 0; ii < 4; ++ii) {
        acc[ii][0] = fmaf(as0[ii], b2.x, acc[ii][0]);
        acc[ii][1] = fmaf(as0[ii], b2.y, acc[ii][1]);
      }
    }
    __syncthreads();
  }

#pragma unroll
  for (int ii = 0; ii < 4; ++ii) {
    const int gr = rowBase + ty * 4 + ii;
    const float sa = scales[pA * NN + gr];
#pragma unroll
    for (int jj = 0; jj < 2; ++jj) {
      const int gc = colBase + tx * 2 + jj;
      const float sb = scales[pB * NN + gc];
      C[gr * NN + gc] = 1.0f - acc[ii][jj] * sa * sb;
    }
  }
}

// ---------------- exact JV shortest-augmenting-path LAP, ONE WAVE per problem ----------
// VERBATIM Round-6 lap (best measured: 5195 us). R5/R6/R7 established this structure
// is within ~10% of its floor; source-level reordering (pipelining, base precompute
// beyond this) is neutral-to-negative. Lane t owns columns/rows 8t..8t+7; zero LDS ops
// in the inner loop; SC-exclusion via vAdj=-INF poison; f64 duals; final assignment =
// unique optimum = reference output.

// bijective LDS index swizzle: owner-lane accesses (stride 8) become conflict-free
__device__ __forceinline__ int SW(int c) { return ((c & 7) << 6) | (c >> 3); }

// full-wave (64-lane) u32 min via DPP; returns broadcast scalar
__device__ __forceinline__ unsigned wave_min_u32(unsigned x) {
  int t;
  t = __builtin_amdgcn_update_dpp((int)x, (int)x, 0x111, 0xf, 0xf, false);  // row_shr:1
  x = ((unsigned)t < x) ? (unsigned)t : x;
  t = __builtin_amdgcn_update_dpp((int)x, (int)x, 0x112, 0xf, 0xf, false);  // row_shr:2
  x = ((unsigned)t < x) ? (unsigned)t : x;
  t = __builtin_amdgcn_update_dpp((int)x, (int)x, 0x114, 0xf, 0xf, false);  // row_shr:4
  x = ((unsigned)t < x) ? (unsigned)t : x;
  t = __builtin_amdgcn_update_dpp((int)x, (int)x, 0x118, 0xf, 0xf, false);  // row_shr:8
  x = ((unsigned)t < x) ? (unsigned)t : x;
  t = __builtin_amdgcn_update_dpp((int)x, (int)x, 0x142, 0xf, 0xf, false);  // row_bcast:15
  x = ((unsigned)t < x) ? (unsigned)t : x;
  t = __builtin_amdgcn_update_dpp((int)x, (int)x, 0x143, 0xf, 0xf, false);  // row_bcast:31
  x = ((unsigned)t < x) ? (unsigned)t : x;
  return (unsigned)__builtin_amdgcn_readlane((int)x, 63);
}

__device__ __forceinline__ double readlane_f64(double x, int lane) {
  const long long b = __double_as_longlong(x);
  const int lo = __builtin_amdgcn_readlane((int)(b & 0xffffffffLL), lane);
  const int hi = __builtin_amdgcn_readlane((int)(b >> 32), lane);
  return __longlong_as_double(((long long)hi << 32) | (unsigned long long)(unsigned)lo);
}

__device__ __forceinline__ unsigned long long f64key(double x) {
  const long long b = __double_as_longlong(x);
  return (b < 0) ? ~(unsigned long long)b
                 : ((unsigned long long)b | 0x8000000000000000ULL);
}

__global__ __launch_bounds__(64) void lap_kernel(
    const float* __restrict__ cost_all, float* __restrict__ out) {
  const int p = blockIdx.x;
  const float* cost = cost_all + (size_t)p * NN * NN;
  float* outp = out + (size_t)p * NN * NN;
  const int tid = threadIdx.x;  // 0..63

  __shared__ double sh_u[NN];        // u[row] at SW(row)
  __shared__ double sh_shortest[NN]; // frozen shortest[col] at SW(col)
  __shared__ int sh_path[NN];        // path[col] at SW(col)
  __shared__ int sh_x[NN];           // col4row[row] at SW(row)
  __shared__ int sh_y[NN];           // row4col[col] at SW(col)

  const double INF = __builtin_inf();

#pragma unroll
  for (int q = 0; q < 8; ++q) {
    const int e = tid * 8 + q;
    sh_x[SW(e)] = -1;
    sh_y[SW(e)] = -1;
    sh_u[SW(e)] = 0.0;
  }
  double myV[8];
#pragma unroll
  for (int q = 0; q < 8; ++q) myV[q] = 0.0;  // v[8*tid+q], owner-only
  __syncthreads();

  for (int cur_row = 0; cur_row < NN; ++cur_row) {
    double selv[8];   // current shortest (INF once in SC); reduce input
    double vAdj[8];   // myV, poisoned to -INF when col enters SC
    double frz[8];    // frozen shortest at SC-add time (= minv then)
    int myPath[8];
    unsigned pl[8];   // payload: (q<<10) | (row4col[col]+1)  (phase-constant)
#pragma unroll
    for (int q = 0; q < 8; ++q) {
      selv[q] = INF;
      vAdj[q] = myV[q];
      frz[q] = 0.0;
      myPath[q] = 0;
    }
#pragma unroll
    for (int q = 0; q < 8; ++q)
      pl[q] = ((unsigned)q << 10) | (unsigned)(sh_y[SW(tid * 8 + q)] + 1);

    unsigned scMask = 0, srMask = 0;
    int i = cur_row;     // uniform
    double minv = 0.0;   // uniform
    int sink = -1;       // uniform
    int pendQ = -1, pendLane = 0;

    while (true) {
      // dependent loads first; all bookkeeping below hides in their shadow
      const float4 c0 = *(const float4*)(cost + (size_t)i * NN + tid * 8);
      const float4 c1 = *(const float4*)(cost + (size_t)i * NN + tid * 8 + 4);
      const double u_i = sh_u[SW(i)];
      if ((i >> 3) == tid) srMask |= 1u << (i & 7);
      if (pendQ >= 0) {
        const bool me = (tid == pendLane);
#define APPLY_SC(K)                                                     \
        if (pendQ == K) {                                               \
          if (me) {                                                     \
            selv[K] = INF; vAdj[K] = -INF; frz[K] = minv;               \
            scMask |= 1u << K;                                          \
          }                                                             \
        }
        APPLY_SC(0) APPLY_SC(1) APPLY_SC(2) APPLY_SC(3)
        APPLY_SC(4) APPLY_SC(5) APPLY_SC(6) APPLY_SC(7)
#undef APPLY_SC
      }
      // load-independent bases, computed in the load shadow:
      // r = cf[q] + ((minv - u_i) - vAdj[q])   [re-associated; final matching is the
      // unique optimum, margins >> accumulated f64 rounding]
      const double mu = minv - u_i;
      double base[8];
#pragma unroll
      for (int q = 0; q < 8; ++q) base[q] = mu - vAdj[q];  // SC cols: +INF
      const float cf[8] = {c0.x, c0.y, c0.z, c0.w, c1.x, c1.y, c1.z, c1.w};
#pragma unroll
      for (int q = 0; q < 8; ++q) {
        const double r = (double)cf[q] + base[q];
        const bool cnd = r < selv[q];
        selv[q] = fmin(selv[q], r);
        myPath[q] = cnd ? i : myPath[q];
      }
      // per-lane tournament over 8 candidates (ties keep lowest q)
      const bool t01 = selv[1] < selv[0];
      double v01 = t01 ? selv[1] : selv[0]; unsigned p01 = t01 ? pl[1] : pl[0];
      const bool t23 = selv[3] < selv[2];
      double v23 = t23 ? selv[3] : selv[2]; unsigned p23 = t23 ? pl[3] : pl[2];
      const bool t45 = selv[5] < selv[4];
      double v45 = t45 ? selv[5] : selv[4]; unsigned p45 = t45 ? pl[5] : pl[4];
      const bool t67 = selv[7] < selv[6];
      double v67 = t67 ? selv[7] : selv[6]; unsigned p67 = t67 ? pl[7] : pl[6];
      const bool ta = v23 < v01;
      const double vab = ta ? v23 : v01; const unsigned pab = ta ? p23 : p01;
      const bool tb = v67 < v45;
      const double vcd = tb ? v67 : v45; const unsigned pcd = tb ? p67 : p45;
      const bool tc = vcd < vab;
      const double lv = tc ? vcd : vab; const unsigned lp = tc ? pcd : pab;
      // exact cross-lane argmin via sortable key
      const unsigned long long kk = f64key(lv);
      const unsigned hi = (unsigned)(kk >> 32);
      const unsigned lo = (unsigned)kk;
      const unsigned minhi = wave_min_u32(hi);
      unsigned long long bal = __ballot(hi == minhi);
      int srcLane;
      if (__popcll(bal) == 1) {  // unique hi-key => unique global min (common case)
        srcLane = __ffsll(bal) - 1;
      } else {
        const unsigned lo2 = (hi == minhi) ? lo : 0xFFFFFFFFu;
        const unsigned minlo = wave_min_u32(lo2);
        bal = __ballot((hi == minhi) && (lo == minlo));
        srcLane = __ffsll(bal) - 1;  // lowest lane = smallest column on exact ties
      }
      // decode payload FIRST so the next iteration's loads (dep: i) issue before
      // the minv readlanes; minv is only needed in the next load's shadow
      const unsigned pw = (unsigned)__builtin_amdgcn_readlane((int)lp, srcLane);
      const int qb = (int)(pw >> 10);
      const int r4 = (int)(pw & 0x3FFu) - 1;
      minv = readlane_f64(lv, srcLane);
      if (r4 < 0) {  // unmatched column: sink (its SC-add is a dual no-op)
        sink = srcLane * 8 + qb;
        break;
      }
      i = r4;
      pendQ = qb;
      pendLane = srcLane;
    }

    // publish frozen shortest + path (only SC cols are ever read back)
#pragma unroll
    for (int q = 0; q < 8; ++q) {
      sh_shortest[SW(tid * 8 + q)] = frz[q];
      sh_path[SW(tid * 8 + q)] = myPath[q];
    }
    __syncthreads();
    // dual updates (before augmentation, matching reference)
#pragma unroll
    for (int q = 0; q < 8; ++q) {
      const int row = tid * 8 + q;
      if (row == cur_row) {
        sh_u[SW(row)] += minv;
      } else if (srMask & (1u << q)) {
        sh_u[SW(row)] += minv - sh_shortest[SW(sh_x[SW(row)])];
      }
      if (scMask & (1u << q)) myV[q] -= minv - frz[q];
    }
    __syncthreads();
    // augment along the alternating path (short chain, lane 0)
    if (tid == 0) {
      int j = sink;
      while (true) {
        const int pi = sh_path[SW(j)];
        sh_y[SW(j)] = pi;
        const int tmp = sh_x[SW(pi)];
        sh_x[SW(pi)] = j;
        j = tmp;
        if (pi == cur_row) break;
      }
    }
    __syncthreads();  // publish matching for next phase
  }

#pragma unroll
  for (int q = 0; q < 8; ++q) {
    const int row = tid * 8 + q;
    outp[(size_t)row * NN + sh_x[SW(row)]] = 1.0f;
  }
}

extern "C" void kernel_launch(void* const* d_in, const int* in_sizes, int n_in,
                              void* d_out, int out_size, void* d_ws, size_t ws_size,
                              hipStream_t stream) {
  const float* un1 = (const float*)d_in[0];
  const float* un2 = (const float*)d_in[1];
  const float* un3 = (const float*)d_in[2];
  float* out = (float*)d_out;

  float* cost = (float*)d_ws;                       // 3 * 512 * 512 floats
  float* scales = cost + (size_t)3 * NN * NN;       // 3 * 512 floats

  hipMemsetAsync(d_out, 0, (size_t)out_size * sizeof(float), stream);

  norm_kernel<<<dim3(NN, 3), 256, 0, stream>>>(un1, un2, un3, scales);
  cost_gemm_kernel<<<dim3(NN / 64, NN / 64, 3), 512, 0, stream>>>(un1, un2, un3, scales, cost);
  lap_kernel<<<3, 64, 0, stream>>>(cost, out);
}